// Round 2
// baseline (228.219 us; speedup 1.0000x reference)
//
#include <hip/hip_runtime.h>
#include <hip/hip_fp16.h>

#define IN_F 4096
#define OUT_F 11008
#define FP_F 256
#define NROWS 512
#define BN 32
#define NTILES (OUT_F / BN)   // 344 n-tiles, x2 m-tiles = 688 blocks

typedef int v4i __attribute__((ext_vector_type(4)));
typedef float v4f __attribute__((ext_vector_type(4)));
typedef _Float16 half8 __attribute__((ext_vector_type(8)));

__device__ __forceinline__ int pack4(v4i a) {
  return (int)((unsigned)(a[0] & 255) | ((unsigned)(a[1] & 255) << 8) |
               ((unsigned)(a[2] & 255) << 16) | ((unsigned)(a[3] & 255) << 24));
}

// One block per row m. Quantize x row to int8 (outlier cols zeroed), store in
// MFMA-fragment-order layout: chunk (mg, kb) of 16 rows x 64 k; within chunk,
// lane = (m&15) + 16*((k>>4)&3), 16 bytes = k&15.
__global__ __launch_bounds__(256) void quant_kernel(
    const float* __restrict__ x, const int* __restrict__ ind,
    signed char* __restrict__ qx, _Float16* __restrict__ act,
    float* __restrict__ xscale)
{
  const int m = blockIdx.x;
  const int t = threadIdx.x;
  __shared__ unsigned char zm[IN_F];
  __shared__ float wmax[4];
  int* zmi = (int*)zm;
  #pragma unroll
  for (int i = 0; i < IN_F / 4 / 256; ++i) zmi[t + i * 256] = 0;
  __syncthreads();
  const int idx = ind[t];
  zm[idx] = 1;  // duplicate ind writes same value: benign
  __syncthreads();

  const float* xr = x + (size_t)m * IN_F;
  float v[16];
  float amax = 0.f;
  const int k0 = t * 16;
  #pragma unroll
  for (int q = 0; q < 4; ++q) {
    v4f f = *(const v4f*)(xr + k0 + q * 4);
    #pragma unroll
    for (int j = 0; j < 4; ++j) {
      float mv = zm[k0 + q * 4 + j] ? 0.f : f[j];
      v[q * 4 + j] = mv;
      amax = fmaxf(amax, fabsf(mv));
    }
  }
  #pragma unroll
  for (int off = 32; off >= 1; off >>= 1)
    amax = fmaxf(amax, __shfl_xor(amax, off));
  if ((t & 63) == 0) wmax[t >> 6] = amax;
  __syncthreads();
  amax = fmaxf(fmaxf(wmax[0], wmax[1]), fmaxf(wmax[2], wmax[3]));
  const float scale = fmaxf(amax / 127.0f, 1e-8f);
  if (t == 0) xscale[m] = scale;
  const float inv = 1.0f / scale;

  union { signed char b[16]; v4i w4; } pk;
  #pragma unroll
  for (int j = 0; j < 16; ++j) {
    float qv = rintf(v[j] * inv);            // round-half-even, like jnp.round
    qv = fminf(fmaxf(qv, -128.f), 127.f);
    pk.b[j] = (signed char)qv;
  }
  const int mg = m >> 4;
  const int kb = t >> 2;
  const int lane = (m & 15) + 16 * (t & 3);
  ((v4i*)qx)[(mg * 64 + kb) * 64 + lane] = pk.w4;

  // outlier activations (original, un-zeroed values), f16
  act[m * FP_F + t] = (_Float16)xr[idx];
}

// Tile 256(M) x 32(N), 4 waves, wave w owns rows [row0, row0+64) x all 32 cols.
// No LDS, no barriers: A fragments read from L2-resident fragment-order qx;
// B fragments read as int32 (4x dwordx4 per fragment) from q_weight and packed
// to int8 in-register. Latency hidden by TLP (688 blocks, low VGPR).
__global__ __launch_bounds__(256) void gemm_kernel(
    const signed char* __restrict__ qx, const int* __restrict__ qw,
    const float* __restrict__ scol, const float* __restrict__ wc,
    const float* __restrict__ bias, const _Float16* __restrict__ act,
    const float* __restrict__ xscale, float* __restrict__ out)
{
  const int tid = threadIdx.x;
  const int w = tid >> 6;
  const int l = tid & 63;
  const int mtile = blockIdx.x & 1;          // pairs share the B tile
  const int ntile = blockIdx.x >> 1;
  const int n0 = ntile * BN;
  const int row0 = mtile * 256 + w * 64;

  const v4i* qx4 = (const v4i*)qx;
  const int aBase = (row0 >> 4) * 4096 + l;  // + mf*4096 + kb*64
  // B fragment source: lane l -> col n0 + nf*16 + (l&15), k-ints (l>>4)*16 + kb*64
  const int* qwb = qw + (size_t)(n0 + (l & 15)) * IN_F + ((l >> 4) << 4);

  v4i acc[4][2] = {};

  #pragma unroll 2
  for (int kb = 0; kb < 64; ++kb) {
    v4i a[4];
    #pragma unroll
    for (int mf = 0; mf < 4; ++mf)
      a[mf] = qx4[aBase + mf * 4096 + kb * 64];
    v4i b[2];
    #pragma unroll
    for (int nf = 0; nf < 2; ++nf) {
      const int* s = qwb + nf * 16 * IN_F + kb * 64;
      v4i r0 = *(const v4i*)(s);
      v4i r1 = *(const v4i*)(s + 4);
      v4i r2 = *(const v4i*)(s + 8);
      v4i r3 = *(const v4i*)(s + 12);
      v4i pb;
      pb[0] = pack4(r0);
      pb[1] = pack4(r1);
      pb[2] = pack4(r2);
      pb[3] = pack4(r3);
      b[nf] = pb;
    }
    #pragma unroll
    for (int mf = 0; mf < 4; ++mf)
      #pragma unroll
      for (int nf = 0; nf < 2; ++nf)
        acc[mf][nf] = __builtin_amdgcn_mfma_i32_16x16x64_i8(
            a[mf], b[nf], acc[mf][nf], 0, 0, 0);
  }

  // epilogue scales
  float sc[2], bs[2];
  #pragma unroll
  for (int nf = 0; nf < 2; ++nf) {
    sc[nf] = scol[n0 + nf * 16 + (l & 15)];
    bs[nf] = bias[n0 + nf * 16 + (l & 15)];
  }
  float xs[4][4];
  #pragma unroll
  for (int mf = 0; mf < 4; ++mf)
    #pragma unroll
    for (int j = 0; j < 4; ++j)
      xs[mf][j] = xscale[row0 + mf * 16 + (l >> 4) * 4 + j];

  v4f facc[4][2];
  #pragma unroll
  for (int mf = 0; mf < 4; ++mf)
    #pragma unroll
    for (int nf = 0; nf < 2; ++nf)
      #pragma unroll
      for (int j = 0; j < 4; ++j)
        facc[mf][nf][j] = (float)acc[mf][nf][j] * xs[mf][j] * sc[nf];

  // outlier fp phase: K=256 in 8 steps of 32, f16 MFMA into same f32 acc
  #pragma unroll
  for (int ks = 0; ks < 8; ++ks) {
    const int kk = ks * 32 + (l >> 4) * 8;
    half8 ah[4];
    #pragma unroll
    for (int mf = 0; mf < 4; ++mf) {
      const int row = row0 + mf * 16 + (l & 15);
      ah[mf] = *(const half8*)(act + row * FP_F + kk);
    }
    half8 bh[2];
    #pragma unroll
    for (int nf = 0; nf < 2; ++nf) {
      const float* wr = wc + (size_t)(n0 + nf * 16 + (l & 15)) * FP_F + kk;
      v4f w0 = *(const v4f*)(wr);
      v4f w1 = *(const v4f*)(wr + 4);
      half8 hb;
      #pragma unroll
      for (int j = 0; j < 4; ++j) {
        hb[j] = (_Float16)w0[j];
        hb[4 + j] = (_Float16)w1[j];
      }
      bh[nf] = hb;
    }
    #pragma unroll
    for (int mf = 0; mf < 4; ++mf)
      #pragma unroll
      for (int nf = 0; nf < 2; ++nf)
        facc[mf][nf] = __builtin_amdgcn_mfma_f32_16x16x32_f16(
            ah[mf], bh[nf], facc[mf][nf], 0, 0, 0);
  }

  // + bias, store
  #pragma unroll
  for (int mf = 0; mf < 4; ++mf)
    #pragma unroll
    for (int nf = 0; nf < 2; ++nf) {
      const int col = n0 + nf * 16 + (l & 15);
      #pragma unroll
      for (int j = 0; j < 4; ++j) {
        const int row = row0 + mf * 16 + (l >> 4) * 4 + j;
        out[(size_t)row * OUT_F + col] = facc[mf][nf][j] + bs[nf];
      }
    }
}

extern "C" void kernel_launch(void* const* d_in, const int* in_sizes, int n_in,
                              void* d_out, int out_size, void* d_ws, size_t ws_size,
                              hipStream_t stream) {
  const float* x      = (const float*)d_in[0];
  const int*   qw     = (const int*)d_in[1];
  const float* scol   = (const float*)d_in[2];
  const float* wcache = (const float*)d_in[3];
  const int*   ind    = (const int*)d_in[4];
  const float* bias   = (const float*)d_in[5];
  float* out = (float*)d_out;

  signed char* qx = (signed char*)d_ws;                                   // 2 MB
  _Float16* act = (_Float16*)((char*)d_ws + (size_t)NROWS * IN_F);        // 256 KB
  float* xscale = (float*)((char*)d_ws + (size_t)NROWS * IN_F + (size_t)NROWS * FP_F * 2);

  quant_kernel<<<NROWS, 256, 0, stream>>>(x, ind, qx, act, xscale);
  gemm_kernel<<<NTILES * 2, 256, 0, stream>>>(qx, qw, scol, wcache, bias, act, xscale, out);
}

// Round 3
// 146.358 us; speedup vs baseline: 1.5593x; 1.5593x over previous
//
#include <hip/hip_runtime.h>
#include <hip/hip_fp16.h>

#define IN_F 4096
#define OUT_F 11008
#define FP_F 256
#define NROWS 512
#define BN 32
#define BM 256

typedef int v4i __attribute__((ext_vector_type(4)));
typedef float v4f __attribute__((ext_vector_type(4)));
typedef _Float16 half8 __attribute__((ext_vector_type(8)));

__device__ __forceinline__ int pack4(v4i a) {
  return (int)((unsigned)(a[0] & 255) | ((unsigned)(a[1] & 255) << 8) |
               ((unsigned)(a[2] & 255) << 16) | ((unsigned)(a[3] & 255) << 24));
}

// One block per row m. Quantize x row to int8 (outlier cols zeroed), store in
// MFMA-fragment-order layout: chunk (mg, kb) of 16 rows x 64 k; within chunk,
// lane = (m&15) + 16*((k>>4)&3), 16 bytes = k&15.
__global__ __launch_bounds__(256) void quant_kernel(
    const float* __restrict__ x, const int* __restrict__ ind,
    signed char* __restrict__ qx, _Float16* __restrict__ act,
    float* __restrict__ xscale)
{
  const int m = blockIdx.x;
  const int t = threadIdx.x;
  __shared__ unsigned char zm[IN_F];
  __shared__ float wmax[4];
  int* zmi = (int*)zm;
  #pragma unroll
  for (int i = 0; i < IN_F / 4 / 256; ++i) zmi[t + i * 256] = 0;
  __syncthreads();
  const int idx = ind[t];
  zm[idx] = 1;  // duplicate ind writes same value: benign
  __syncthreads();

  const float* xr = x + (size_t)m * IN_F;
  float v[16];
  float amax = 0.f;
  const int k0 = t * 16;
  #pragma unroll
  for (int q = 0; q < 4; ++q) {
    v4f f = *(const v4f*)(xr + k0 + q * 4);
    #pragma unroll
    for (int j = 0; j < 4; ++j) {
      float mv = zm[k0 + q * 4 + j] ? 0.f : f[j];
      v[q * 4 + j] = mv;
      amax = fmaxf(amax, fabsf(mv));
    }
  }
  #pragma unroll
  for (int off = 32; off >= 1; off >>= 1)
    amax = fmaxf(amax, __shfl_xor(amax, off));
  if ((t & 63) == 0) wmax[t >> 6] = amax;
  __syncthreads();
  amax = fmaxf(fmaxf(wmax[0], wmax[1]), fmaxf(wmax[2], wmax[3]));
  const float scale = fmaxf(amax / 127.0f, 1e-8f);
  if (t == 0) xscale[m] = scale;
  const float inv = 1.0f / scale;

  union { signed char b[16]; v4i w4; } pk;
  #pragma unroll
  for (int j = 0; j < 16; ++j) {
    float qv = rintf(v[j] * inv);            // round-half-even, like jnp.round
    qv = fminf(fmaxf(qv, -128.f), 127.f);
    pk.b[j] = (signed char)qv;
  }
  const int mg = m >> 4;
  const int kb = t >> 2;
  const int lane = (m & 15) + 16 * (t & 3);
  ((v4i*)qx)[(mg * 64 + kb) * 64 + lane] = pk.w4;

  // outlier activations (original, un-zeroed values), f16
  act[m * FP_F + t] = (_Float16)xr[idx];
}

// Tile 256(M) x 32(N), 4 waves, wave w owns rows [row0, row0+64) x 32 cols.
// B (int32) loaded COALESCED (full 64B lines per instruction), packed to int8
// in-register, staged to a 2x2KB LDS double buffer in MFMA fragment order.
// 4-deep register prefetch; raw s_barrier + lgkmcnt(0) only (NO vmcnt drain),
// so global loads stay ~3 K-steps in flight across barriers.
__global__ __launch_bounds__(256) void gemm_kernel(
    const signed char* __restrict__ qx, const int* __restrict__ qw,
    const float* __restrict__ scol, const float* __restrict__ wc,
    const float* __restrict__ bias, const _Float16* __restrict__ act,
    const float* __restrict__ xscale, float* __restrict__ out)
{
  __shared__ __align__(16) signed char blds[2][2048];
  const int tid = threadIdx.x;
  const int w = tid >> 6;
  const int l = tid & 63;
  const int mtile = blockIdx.x & 1;   // fast bit: pair sharing B runs adjacent
  const int ntile = blockIdx.x >> 1;
  const int n0 = ntile * BN;
  const int row0 = mtile * BM + w * 64;

  // B staging: thread t -> row r = t>>3 (0..31), load j in {0,1}:
  // ints [kb*64 + j*32 + (t&7)*4, +4)  (16B, 8 lanes cover 128B contiguous)
  const int r = tid >> 3;
  const int* bsrc = qw + (size_t)(n0 + r) * IN_F + (tid & 7) * 4;
  // LDS fragment dest: chunk c=r>>4, slot=(r&15)+16*g, g=2j+((t&7)>>2), byte=(t&3)*4
  signed char* bw0 = &blds[0][0] + (r >> 4) * 1024 +
                     ((r & 15) + 16 * ((tid & 7) >> 2)) * 16 + (tid & 3) * 4;

  const v4i* qx4 = (const v4i*)qx;
  const int aBase = (row0 >> 4) * 4096 + l;

  v4i gr[4][2];      // B int32 prefetch ring, 4 K-steps deep
  v4i ar[2][4];      // A fragment double buffer

  #pragma unroll
  for (int s = 0; s < 4; ++s) {
    gr[s][0] = *(const v4i*)(bsrc + s * 64);
    gr[s][1] = *(const v4i*)(bsrc + s * 64 + 32);
  }
  #pragma unroll
  for (int mf = 0; mf < 4; ++mf)
    ar[0][mf] = qx4[aBase + mf * 4096];

  // stage K-step 0 into buf 0
  *(int*)(bw0)       = pack4(gr[0][0]);
  *(int*)(bw0 + 512) = pack4(gr[0][1]);
  asm volatile("s_waitcnt lgkmcnt(0)" ::: "memory");
  __builtin_amdgcn_s_barrier();

  v4i acc[4][2] = {};

  for (int kb = 0; kb < 64; ++kb) {
    // issue B loads for kb+4 into freed slot kb&3
    const int kf = (kb + 4 < 64) ? kb + 4 : 63;
    gr[kb & 3][0] = *(const v4i*)(bsrc + kf * 64);
    gr[kb & 3][1] = *(const v4i*)(bsrc + kf * 64 + 32);
    // A prefetch for kb+1
    const int ka = (kb + 1 < 64) ? kb + 1 : 63;
    #pragma unroll
    for (int mf = 0; mf < 4; ++mf)
      ar[(kb + 1) & 1][mf] = qx4[aBase + mf * 4096 + ka * 64];
    // pack kb+1 data (loaded 3 iters ago) into buf (kb+1)&1
    {
      signed char* d = bw0 + ((kb + 1) & 1) * 2048;
      *(int*)(d)       = pack4(gr[(kb + 1) & 3][0]);
      *(int*)(d + 512) = pack4(gr[(kb + 1) & 3][1]);
    }
    // read kb fragments from buf kb&1, MFMA
    const signed char* rb = &blds[kb & 1][0];
    v4i b[2];
    #pragma unroll
    for (int nf = 0; nf < 2; ++nf)
      b[nf] = *(const v4i*)(rb + nf * 1024 + l * 16);
    #pragma unroll
    for (int mf = 0; mf < 4; ++mf)
      #pragma unroll
      for (int nf = 0; nf < 2; ++nf)
        acc[mf][nf] = __builtin_amdgcn_mfma_i32_16x16x64_i8(
            ar[kb & 1][mf], b[nf], acc[mf][nf], 0, 0, 0);
    asm volatile("s_waitcnt lgkmcnt(0)" ::: "memory");
    __builtin_amdgcn_s_barrier();
  }

  // epilogue scales
  float sc[2], bs[2];
  #pragma unroll
  for (int nf = 0; nf < 2; ++nf) {
    sc[nf] = scol[n0 + nf * 16 + (l & 15)];
    bs[nf] = bias[n0 + nf * 16 + (l & 15)];
  }
  float xs[4][4];
  #pragma unroll
  for (int mf = 0; mf < 4; ++mf)
    #pragma unroll
    for (int j = 0; j < 4; ++j)
      xs[mf][j] = xscale[row0 + mf * 16 + (l >> 4) * 4 + j];

  v4f facc[4][2];
  #pragma unroll
  for (int mf = 0; mf < 4; ++mf)
    #pragma unroll
    for (int nf = 0; nf < 2; ++nf)
      #pragma unroll
      for (int j = 0; j < 4; ++j)
        facc[mf][nf][j] = (float)acc[mf][nf][j] * xs[mf][j] * sc[nf];

  // outlier fp phase: K=256 in 8 steps of 32, f16 MFMA into same f32 acc
  #pragma unroll
  for (int ks = 0; ks < 8; ++ks) {
    const int kk = ks * 32 + (l >> 4) * 8;
    half8 ah[4];
    #pragma unroll
    for (int mf = 0; mf < 4; ++mf) {
      const int row = row0 + mf * 16 + (l & 15);
      ah[mf] = *(const half8*)(act + row * FP_F + kk);
    }
    half8 bh[2];
    #pragma unroll
    for (int nf = 0; nf < 2; ++nf) {
      const float* wr = wc + (size_t)(n0 + nf * 16 + (l & 15)) * FP_F + kk;
      v4f w0 = *(const v4f*)(wr);
      v4f w1 = *(const v4f*)(wr + 4);
      half8 hb;
      #pragma unroll
      for (int j = 0; j < 4; ++j) {
        hb[j] = (_Float16)w0[j];
        hb[4 + j] = (_Float16)w1[j];
      }
      bh[nf] = hb;
    }
    #pragma unroll
    for (int mf = 0; mf < 4; ++mf)
      #pragma unroll
      for (int nf = 0; nf < 2; ++nf)
        facc[mf][nf] = __builtin_amdgcn_mfma_f32_16x16x32_f16(
            ah[mf], bh[nf], facc[mf][nf], 0, 0, 0);
  }

  // + bias, store
  #pragma unroll
  for (int mf = 0; mf < 4; ++mf)
    #pragma unroll
    for (int nf = 0; nf < 2; ++nf) {
      const int col = n0 + nf * 16 + (l & 15);
      #pragma unroll
      for (int j = 0; j < 4; ++j) {
        const int row = row0 + mf * 16 + (l >> 4) * 4 + j;
        out[(size_t)row * OUT_F + col] = facc[mf][nf][j] + bs[nf];
      }
    }
}

extern "C" void kernel_launch(void* const* d_in, const int* in_sizes, int n_in,
                              void* d_out, int out_size, void* d_ws, size_t ws_size,
                              hipStream_t stream) {
  const float* x      = (const float*)d_in[0];
  const int*   qw     = (const int*)d_in[1];
  const float* scol   = (const float*)d_in[2];
  const float* wcache = (const float*)d_in[3];
  const int*   ind    = (const int*)d_in[4];
  const float* bias   = (const float*)d_in[5];
  float* out = (float*)d_out;

  signed char* qx = (signed char*)d_ws;                                   // 2 MB
  _Float16* act = (_Float16*)((char*)d_ws + (size_t)NROWS * IN_F);        // 256 KB
  float* xscale = (float*)((char*)d_ws + (size_t)NROWS * IN_F + (size_t)NROWS * FP_F * 2);

  quant_kernel<<<NROWS, 256, 0, stream>>>(x, ind, qx, act, xscale);
  gemm_kernel<<<(OUT_F / BN) * 2, 256, 0, stream>>>(qx, qw, scol, wcache, bias, act, xscale, out);
}

// Round 4
// 140.361 us; speedup vs baseline: 1.6259x; 1.0427x over previous
//
#include <hip/hip_runtime.h>
#include <hip/hip_fp16.h>

#define IN_F 4096
#define OUT_F 11008
#define FP_F 256
#define NROWS 512
#define BN 32
#define BM 256
#define NGB (OUT_F / 16)   // 688 q_weight row-groups

typedef int v4i __attribute__((ext_vector_type(4)));
typedef float v4f __attribute__((ext_vector_type(4)));
typedef _Float16 half8 __attribute__((ext_vector_type(8)));

__device__ __forceinline__ int pack4(v4i a) {
  return (int)((unsigned)(a[0] & 255) | ((unsigned)(a[1] & 255) << 8) |
               ((unsigned)(a[2] & 255) << 16) | ((unsigned)(a[3] & 255) << 24));
}

// ---------------- quant: x -> int8 qx in MFMA fragment layout ----------------
__global__ __launch_bounds__(256) void quant_kernel(
    const float* __restrict__ x, const int* __restrict__ ind,
    signed char* __restrict__ qx, _Float16* __restrict__ act,
    float* __restrict__ xscale)
{
  const int m = blockIdx.x;
  const int t = threadIdx.x;
  __shared__ unsigned char zm[IN_F];
  __shared__ float wmax[4];
  int* zmi = (int*)zm;
  #pragma unroll
  for (int i = 0; i < IN_F / 4 / 256; ++i) zmi[t + i * 256] = 0;
  __syncthreads();
  const int idx = ind[t];
  zm[idx] = 1;
  __syncthreads();

  const float* xr = x + (size_t)m * IN_F;
  float v[16];
  float amax = 0.f;
  const int k0 = t * 16;
  #pragma unroll
  for (int q = 0; q < 4; ++q) {
    v4f f = *(const v4f*)(xr + k0 + q * 4);
    #pragma unroll
    for (int j = 0; j < 4; ++j) {
      float mv = zm[k0 + q * 4 + j] ? 0.f : f[j];
      v[q * 4 + j] = mv;
      amax = fmaxf(amax, fabsf(mv));
    }
  }
  #pragma unroll
  for (int off = 32; off >= 1; off >>= 1)
    amax = fmaxf(amax, __shfl_xor(amax, off));
  if ((t & 63) == 0) wmax[t >> 6] = amax;
  __syncthreads();
  amax = fmaxf(fmaxf(wmax[0], wmax[1]), fmaxf(wmax[2], wmax[3]));
  const float scale = fmaxf(amax / 127.0f, 1e-8f);
  if (t == 0) xscale[m] = scale;
  const float inv = 1.0f / scale;

  union { signed char b[16]; v4i w4; } pk;
  #pragma unroll
  for (int j = 0; j < 16; ++j) {
    float qv = rintf(v[j] * inv);
    qv = fminf(fmaxf(qv, -128.f), 127.f);
    pk.b[j] = (signed char)qv;
  }
  const int mg = m >> 4;
  const int kb = t >> 2;
  const int lane = (m & 15) + 16 * (t & 3);
  ((v4i*)qx)[(mg * 64 + kb) * 64 + lane] = pk.w4;

  act[m * FP_F + t] = (_Float16)xr[idx];
}

// ---------------- pack: q_weight int32 -> int8 fragment layout ----------------
// Block (ng, Q): rows [ng*16, +16), ints [Q*1024, +1024). Per iteration r the
// 256 threads read 1024 consecutive ints of one row (fully coalesced 1KB/wave),
// pack4 -> one 4-B store into the fragment position.
__global__ __launch_bounds__(256) void pack_kernel(
    const int* __restrict__ qw, signed char* __restrict__ qb)
{
  const int ng = blockIdx.x >> 2;
  const int Q  = blockIdx.x & 3;
  const int t  = threadIdx.x;
  const int kb = Q * 16 + (t >> 4);
  const int g  = (t >> 2) & 3;
  const int* src = qw + (size_t)(ng * 16) * IN_F + Q * 1024 + t * 4;
  int* dst = (int*)qb + ((size_t)(ng * 64 + kb) * 64 + 16 * g) * 4 + (t & 3);
  #pragma unroll
  for (int r = 0; r < 16; ++r) {
    v4i v = *(const v4i*)(src + (size_t)r * IN_F);
    dst[r * 4] = pack4(v);
  }
}

// ---------------- gemm: no LDS, no barriers, depth-4 register ring ----------
// Tile 256(M) x 32(N), 4 waves; wave w owns rows [row0,row0+64) x 32 cols.
// A from qx (L2), B from qb (L3) -- both fragment-contiguous dwordx4 loads.
__global__ __launch_bounds__(256) void gemm_kernel(
    const signed char* __restrict__ qx, const signed char* __restrict__ qb,
    const float* __restrict__ scol, const float* __restrict__ wc,
    const float* __restrict__ bias, const _Float16* __restrict__ act,
    const float* __restrict__ xscale, float* __restrict__ out)
{
  const int tid = threadIdx.x;
  const int w = tid >> 6;
  const int l = tid & 63;
  // bijective XCD swizzle (688 = 8*86): pairs sharing a B panel run
  // back-to-back on the same XCD.
  const int orig = blockIdx.x;
  const int wgid = (orig & 7) * 86 + (orig >> 3);
  const int mtile = wgid & 1;
  const int ntile = wgid >> 1;
  const int n0 = ntile * BN;
  const int row0 = mtile * BM + w * 64;

  const v4i* qx4 = (const v4i*)qx;
  const v4i* qb4 = (const v4i*)qb;
  const int aBase = (mtile * 16 + w * 4) * 4096 + l;  // + mf*4096 + kb*64
  const int bBase = (ntile * 2) * 4096 + l;           // + nf*4096 + kb*64

  v4i a[4][4], b[4][2];
  #pragma unroll
  for (int s = 0; s < 3; ++s) {
    #pragma unroll
    for (int mf = 0; mf < 4; ++mf) a[s][mf] = qx4[aBase + mf * 4096 + s * 64];
    #pragma unroll
    for (int nf = 0; nf < 2; ++nf) b[s][nf] = qb4[bBase + nf * 4096 + s * 64];
  }

  v4i acc[4][2] = {};

#define KSTEP(KB, S, SP) do {                                                 \
    const int kf = ((KB) + 3 < 64) ? (KB) + 3 : 63;                           \
    _Pragma("unroll")                                                         \
    for (int mf = 0; mf < 4; ++mf)                                            \
      a[SP][mf] = qx4[aBase + mf * 4096 + kf * 64];                           \
    _Pragma("unroll")                                                         \
    for (int nf = 0; nf < 2; ++nf)                                            \
      b[SP][nf] = qb4[bBase + nf * 4096 + kf * 64];                           \
    _Pragma("unroll")                                                         \
    for (int mf = 0; mf < 4; ++mf)                                            \
      _Pragma("unroll")                                                       \
      for (int nf = 0; nf < 2; ++nf)                                          \
        acc[mf][nf] = __builtin_amdgcn_mfma_i32_16x16x64_i8(                  \
            a[S][mf], b[S][nf], acc[mf][nf], 0, 0, 0);                        \
  } while (0)

  for (int t2 = 0; t2 < 64; t2 += 4) {
    KSTEP(t2 + 0, 0, 3);
    KSTEP(t2 + 1, 1, 0);
    KSTEP(t2 + 2, 2, 1);
    KSTEP(t2 + 3, 3, 2);
  }
#undef KSTEP

  // epilogue scales
  float sc[2], bs[2];
  #pragma unroll
  for (int nf = 0; nf < 2; ++nf) {
    sc[nf] = scol[n0 + nf * 16 + (l & 15)];
    bs[nf] = bias[n0 + nf * 16 + (l & 15)];
  }
  float xs[4][4];
  #pragma unroll
  for (int mf = 0; mf < 4; ++mf)
    #pragma unroll
    for (int j = 0; j < 4; ++j)
      xs[mf][j] = xscale[row0 + mf * 16 + (l >> 4) * 4 + j];

  v4f facc[4][2];
  #pragma unroll
  for (int mf = 0; mf < 4; ++mf)
    #pragma unroll
    for (int nf = 0; nf < 2; ++nf)
      #pragma unroll
      for (int j = 0; j < 4; ++j)
        facc[mf][nf][j] = (float)acc[mf][nf][j] * xs[mf][j] * sc[nf];

  // outlier fp phase: K=256 in 8 steps of 32
  #pragma unroll
  for (int ks = 0; ks < 8; ++ks) {
    const int kk = ks * 32 + (l >> 4) * 8;
    half8 ah[4];
    #pragma unroll
    for (int mf = 0; mf < 4; ++mf) {
      const int row = row0 + mf * 16 + (l & 15);
      ah[mf] = *(const half8*)(act + row * FP_F + kk);
    }
    half8 bh[2];
    #pragma unroll
    for (int nf = 0; nf < 2; ++nf) {
      const float* wr = wc + (size_t)(n0 + nf * 16 + (l & 15)) * FP_F + kk;
      v4f w0 = *(const v4f*)(wr);
      v4f w1 = *(const v4f*)(wr + 4);
      half8 hb;
      #pragma unroll
      for (int j = 0; j < 4; ++j) {
        hb[j] = (_Float16)w0[j];
        hb[4 + j] = (_Float16)w1[j];
      }
      bh[nf] = hb;
    }
    #pragma unroll
    for (int mf = 0; mf < 4; ++mf)
      #pragma unroll
      for (int nf = 0; nf < 2; ++nf)
        facc[mf][nf] = __builtin_amdgcn_mfma_f32_16x16x32_f16(
            ah[mf], bh[nf], facc[mf][nf], 0, 0, 0);
  }

  #pragma unroll
  for (int mf = 0; mf < 4; ++mf)
    #pragma unroll
    for (int nf = 0; nf < 2; ++nf) {
      const int col = n0 + nf * 16 + (l & 15);
      #pragma unroll
      for (int j = 0; j < 4; ++j) {
        const int row = row0 + mf * 16 + (l >> 4) * 4 + j;
        out[(size_t)row * OUT_F + col] = facc[mf][nf][j] + bs[nf];
      }
    }
}

// ---------------- fallback (round-3 path) if ws is too small ----------------
__global__ __launch_bounds__(256) void gemm_fallback(
    const signed char* __restrict__ qx, const int* __restrict__ qw,
    const float* __restrict__ scol, const float* __restrict__ wc,
    const float* __restrict__ bias, const _Float16* __restrict__ act,
    const float* __restrict__ xscale, float* __restrict__ out)
{
  __shared__ __align__(16) signed char blds[2][2048];
  const int tid = threadIdx.x;
  const int w = tid >> 6;
  const int l = tid & 63;
  const int mtile = blockIdx.x & 1;
  const int ntile = blockIdx.x >> 1;
  const int n0 = ntile * BN;
  const int row0 = mtile * BM + w * 64;

  const int r = tid >> 3;
  const int* bsrc = qw + (size_t)(n0 + r) * IN_F + (tid & 7) * 4;
  signed char* bw0 = &blds[0][0] + (r >> 4) * 1024 +
                     ((r & 15) + 16 * ((tid & 7) >> 2)) * 16 + (tid & 3) * 4;

  const v4i* qx4 = (const v4i*)qx;
  const int aBase = (row0 >> 4) * 4096 + l;

  v4i gr[4][2];
  v4i ar[2][4];

  #pragma unroll
  for (int s = 0; s < 4; ++s) {
    gr[s][0] = *(const v4i*)(bsrc + s * 64);
    gr[s][1] = *(const v4i*)(bsrc + s * 64 + 32);
  }
  #pragma unroll
  for (int mf = 0; mf < 4; ++mf)
    ar[0][mf] = qx4[aBase + mf * 4096];

  *(int*)(bw0)       = pack4(gr[0][0]);
  *(int*)(bw0 + 512) = pack4(gr[0][1]);
  asm volatile("s_waitcnt lgkmcnt(0)" ::: "memory");
  __builtin_amdgcn_s_barrier();

  v4i acc[4][2] = {};

  for (int kb = 0; kb < 64; ++kb) {
    const int kf = (kb + 4 < 64) ? kb + 4 : 63;
    gr[kb & 3][0] = *(const v4i*)(bsrc + kf * 64);
    gr[kb & 3][1] = *(const v4i*)(bsrc + kf * 64 + 32);
    const int ka = (kb + 1 < 64) ? kb + 1 : 63;
    #pragma unroll
    for (int mf = 0; mf < 4; ++mf)
      ar[(kb + 1) & 1][mf] = qx4[aBase + mf * 4096 + ka * 64];
    {
      signed char* d = bw0 + ((kb + 1) & 1) * 2048;
      *(int*)(d)       = pack4(gr[(kb + 1) & 3][0]);
      *(int*)(d + 512) = pack4(gr[(kb + 1) & 3][1]);
    }
    const signed char* rb = &blds[kb & 1][0];
    v4i b[2];
    #pragma unroll
    for (int nf = 0; nf < 2; ++nf)
      b[nf] = *(const v4i*)(rb + nf * 1024 + l * 16);
    #pragma unroll
    for (int mf = 0; mf < 4; ++mf)
      #pragma unroll
      for (int nf = 0; nf < 2; ++nf)
        acc[mf][nf] = __builtin_amdgcn_mfma_i32_16x16x64_i8(
            ar[kb & 1][mf], b[nf], acc[mf][nf], 0, 0, 0);
    asm volatile("s_waitcnt lgkmcnt(0)" ::: "memory");
    __builtin_amdgcn_s_barrier();
  }

  float sc[2], bs[2];
  #pragma unroll
  for (int nf = 0; nf < 2; ++nf) {
    sc[nf] = scol[n0 + nf * 16 + (l & 15)];
    bs[nf] = bias[n0 + nf * 16 + (l & 15)];
  }
  float xs[4][4];
  #pragma unroll
  for (int mf = 0; mf < 4; ++mf)
    #pragma unroll
    for (int j = 0; j < 4; ++j)
      xs[mf][j] = xscale[row0 + mf * 16 + (l >> 4) * 4 + j];

  v4f facc[4][2];
  #pragma unroll
  for (int mf = 0; mf < 4; ++mf)
    #pragma unroll
    for (int nf = 0; nf < 2; ++nf)
      #pragma unroll
      for (int j = 0; j < 4; ++j)
        facc[mf][nf][j] = (float)acc[mf][nf][j] * xs[mf][j] * sc[nf];

  #pragma unroll
  for (int ks = 0; ks < 8; ++ks) {
    const int kk = ks * 32 + (l >> 4) * 8;
    half8 ah[4];
    #pragma unroll
    for (int mf = 0; mf < 4; ++mf) {
      const int row = row0 + mf * 16 + (l & 15);
      ah[mf] = *(const half8*)(act + row * FP_F + kk);
    }
    half8 bh[2];
    #pragma unroll
    for (int nf = 0; nf < 2; ++nf) {
      const float* wr = wc + (size_t)(n0 + nf * 16 + (l & 15)) * FP_F + kk;
      v4f w0 = *(const v4f*)(wr);
      v4f w1 = *(const v4f*)(wr + 4);
      half8 hb;
      #pragma unroll
      for (int j = 0; j < 4; ++j) {
        hb[j] = (_Float16)w0[j];
        hb[4 + j] = (_Float16)w1[j];
      }
      bh[nf] = hb;
    }
    #pragma unroll
    for (int mf = 0; mf < 4; ++mf)
      #pragma unroll
      for (int nf = 0; nf < 2; ++nf)
        facc[mf][nf] = __builtin_amdgcn_mfma_f32_16x16x32_f16(
            ah[mf], bh[nf], facc[mf][nf], 0, 0, 0);
  }

  #pragma unroll
  for (int mf = 0; mf < 4; ++mf)
    #pragma unroll
    for (int nf = 0; nf < 2; ++nf) {
      const int col = n0 + nf * 16 + (l & 15);
      #pragma unroll
      for (int j = 0; j < 4; ++j) {
        const int row = row0 + mf * 16 + (l >> 4) * 4 + j;
        out[(size_t)row * OUT_F + col] = facc[mf][nf][j] + bs[nf];
      }
    }
}

extern "C" void kernel_launch(void* const* d_in, const int* in_sizes, int n_in,
                              void* d_out, int out_size, void* d_ws, size_t ws_size,
                              hipStream_t stream) {
  const float* x      = (const float*)d_in[0];
  const int*   qw     = (const int*)d_in[1];
  const float* scol   = (const float*)d_in[2];
  const float* wcache = (const float*)d_in[3];
  const int*   ind    = (const int*)d_in[4];
  const float* bias   = (const float*)d_in[5];
  float* out = (float*)d_out;

  const size_t qx_off  = 0;
  const size_t act_off = (size_t)NROWS * IN_F;                      // 2 MB
  const size_t xs_off  = act_off + (size_t)NROWS * FP_F * 2;        // +256 KB
  const size_t qb_off  = xs_off + (size_t)NROWS * 4;                // +2 KB
  const size_t need    = qb_off + (size_t)OUT_F * IN_F;             // +45 MB

  signed char* qx = (signed char*)d_ws + qx_off;
  _Float16* act   = (_Float16*)((char*)d_ws + act_off);
  float* xscale   = (float*)((char*)d_ws + xs_off);
  signed char* qb = (signed char*)d_ws + qb_off;

  quant_kernel<<<NROWS, 256, 0, stream>>>(x, ind, qx, act, xscale);
  if (ws_size >= need) {
    pack_kernel<<<NGB * 4, 256, 0, stream>>>(qw, qb);
    gemm_kernel<<<(OUT_F / BN) * 2, 256, 0, stream>>>(
        qx, qb, scol, wcache, bias, act, xscale, out);
  } else {
    gemm_fallback<<<(OUT_F / BN) * 2, 256, 0, stream>>>(
        qx, qw, scol, wcache, bias, act, xscale, out);
  }
}

// Round 5
// 112.653 us; speedup vs baseline: 2.0259x; 1.2460x over previous
//
#include <hip/hip_runtime.h>
#include <hip/hip_fp16.h>

#define IN_F 4096
#define OUT_F 11008
#define FP_F 256
#define NROWS 512
#define BN 64
#define BM 128
#define NPACK ((OUT_F / 16) * 4)      // 2752 pack blocks
#define NGEMM ((OUT_F / BN) * (NROWS / BM))  // 688

typedef int v4i __attribute__((ext_vector_type(4)));
typedef float v4f __attribute__((ext_vector_type(4)));
typedef _Float16 half8 __attribute__((ext_vector_type(8)));

__device__ __forceinline__ int pack4(v4i a) {
  return (int)((unsigned)(a[0] & 255) | ((unsigned)(a[1] & 255) << 8) |
               ((unsigned)(a[2] & 255) << 16) | ((unsigned)(a[3] & 255) << 24));
}

// Fused prep: blocks [0,NROWS) quantize x rows -> int8 qx (fragment layout),
// blocks [NROWS, NROWS+NPACK) pack q_weight int32 -> int8 qb (fragment layout).
__global__ __launch_bounds__(256) void prep_kernel(
    const float* __restrict__ x, const int* __restrict__ ind,
    const int* __restrict__ qw, signed char* __restrict__ qx,
    _Float16* __restrict__ act, float* __restrict__ xscale,
    signed char* __restrict__ qb)
{
  const int t = threadIdx.x;
  if (blockIdx.x < NROWS) {
    // ---------------- quant ----------------
    const int m = blockIdx.x;
    __shared__ unsigned char zm[IN_F];
    __shared__ float wmax[4];
    int* zmi = (int*)zm;
    #pragma unroll
    for (int i = 0; i < IN_F / 4 / 256; ++i) zmi[t + i * 256] = 0;
    __syncthreads();
    const int idx = ind[t];
    zm[idx] = 1;
    __syncthreads();

    const float* xr = x + (size_t)m * IN_F;
    float v[16];
    float amax = 0.f;
    const int k0 = t * 16;
    #pragma unroll
    for (int q = 0; q < 4; ++q) {
      v4f f = *(const v4f*)(xr + k0 + q * 4);
      #pragma unroll
      for (int j = 0; j < 4; ++j) {
        float mv = zm[k0 + q * 4 + j] ? 0.f : f[j];
        v[q * 4 + j] = mv;
        amax = fmaxf(amax, fabsf(mv));
      }
    }
    #pragma unroll
    for (int off = 32; off >= 1; off >>= 1)
      amax = fmaxf(amax, __shfl_xor(amax, off));
    if ((t & 63) == 0) wmax[t >> 6] = amax;
    __syncthreads();
    amax = fmaxf(fmaxf(wmax[0], wmax[1]), fmaxf(wmax[2], wmax[3]));
    const float scale = fmaxf(amax / 127.0f, 1e-8f);
    if (t == 0) xscale[m] = scale;
    const float inv = 1.0f / scale;

    union { signed char b[16]; v4i w4; } pk;
    #pragma unroll
    for (int j = 0; j < 16; ++j) {
      float qv = rintf(v[j] * inv);
      qv = fminf(fmaxf(qv, -128.f), 127.f);
      pk.b[j] = (signed char)qv;
    }
    const int mg = m >> 4;
    const int kb = t >> 2;
    const int lane = (m & 15) + 16 * (t & 3);
    ((v4i*)qx)[(mg * 64 + kb) * 64 + lane] = pk.w4;

    act[m * FP_F + t] = (_Float16)xr[idx];
  } else {
    // ---------------- pack ----------------
    const int p = blockIdx.x - NROWS;
    const int ng = p >> 2;            // 16-row group
    const int Q  = p & 3;             // 1024-int span of the row
    const int r2 = t >> 7;            // 0..1
    const int tt = t & 127;           // covers 1024 ints (8 per thread)
    const int i0 = tt * 8;            // int (=packed byte) offset in span
    const int kb = Q * 16 + (i0 >> 6);
    const int g  = (i0 >> 4) & 3;
    const int hb = i0 & 15;           // 0 or 8
    const int* src0 = qw + (size_t)(ng * 16) * IN_F + Q * 1024 + i0;
    signed char* dst0 = qb + ((size_t)(ng * 64 + kb) * 64 + 16 * g) * 16 + hb;
    #pragma unroll
    for (int it = 0; it < 8; ++it) {
      const int rr = it * 2 + r2;     // row within group, 0..15
      const int* s = src0 + (size_t)rr * IN_F;
      v4i v0 = *(const v4i*)(s);
      v4i v1 = *(const v4i*)(s + 4);
      int2 d;
      d.x = pack4(v0);
      d.y = pack4(v1);
      *(int2*)(dst0 + rr * 16) = d;
    }
  }
}

// GEMM: 128(M) x 64(N) tile, 4 waves; wave w owns rows [row0,row0+32) x 64 cols.
// No LDS, no barriers. Depth-4 register ring for A(2/step) and B(4/step);
// prefetch k+3 issued at top of each step into the freed slot -> ~3 K-steps
// (~500cy) latency coverage with counted vmcnt waits.
__global__ __launch_bounds__(256, 3) void gemm_kernel(
    const signed char* __restrict__ qx, const signed char* __restrict__ qb,
    const float* __restrict__ scol, const float* __restrict__ wc,
    const float* __restrict__ bias, const _Float16* __restrict__ act,
    const float* __restrict__ xscale, float* __restrict__ out)
{
  const int tid = threadIdx.x;
  const int w = tid >> 6;
  const int l = tid & 63;
  // bijective XCD swizzle (688 = 8*86): the 4 msegs of an ntile are
  // consecutive wgids on one XCD -> B panel L2-hits after first mseg.
  const int orig = blockIdx.x;
  const int wgid = (orig & 7) * 86 + (orig >> 3);
  const int mseg = wgid & 3;
  const int ntile = wgid >> 2;
  const int n0 = ntile * BN;
  const int row0 = mseg * BM + w * 32;

  const v4i* qx4 = (const v4i*)qx;
  const v4i* qb4 = (const v4i*)qb;
  const int aBase = (row0 >> 4) * 4096 + l;   // + mf*4096 + kb*64
  const int bBase = (ntile * 4) * 4096 + l;   // + nf*4096 + kb*64

  v4i a[4][2], b[4][4];
  #pragma unroll
  for (int s = 0; s < 3; ++s) {
    #pragma unroll
    for (int mf = 0; mf < 2; ++mf) a[s][mf] = qx4[aBase + mf * 4096 + s * 64];
    #pragma unroll
    for (int nf = 0; nf < 4; ++nf) b[s][nf] = qb4[bBase + nf * 4096 + s * 64];
  }

  v4i acc[2][4] = {};

#define KSTEP(KB, S, SP) do {                                                 \
    const int kf = ((KB) + 3 < 64) ? (KB) + 3 : 63;                           \
    _Pragma("unroll")                                                         \
    for (int mf = 0; mf < 2; ++mf)                                            \
      a[SP][mf] = qx4[aBase + mf * 4096 + kf * 64];                           \
    _Pragma("unroll")                                                         \
    for (int nf = 0; nf < 4; ++nf)                                            \
      b[SP][nf] = qb4[bBase + nf * 4096 + kf * 64];                           \
    _Pragma("unroll")                                                         \
    for (int mf = 0; mf < 2; ++mf)                                            \
      _Pragma("unroll")                                                       \
      for (int nf = 0; nf < 4; ++nf)                                          \
        acc[mf][nf] = __builtin_amdgcn_mfma_i32_16x16x64_i8(                  \
            a[S][mf], b[S][nf], acc[mf][nf], 0, 0, 0);                        \
  } while (0)

  for (int t2 = 0; t2 < 64; t2 += 4) {
    KSTEP(t2 + 0, 0, 3);
    KSTEP(t2 + 1, 1, 0);
    KSTEP(t2 + 2, 2, 1);
    KSTEP(t2 + 3, 3, 2);
  }
#undef KSTEP

  // epilogue scales
  float sc[4], bs[4];
  #pragma unroll
  for (int nf = 0; nf < 4; ++nf) {
    sc[nf] = scol[n0 + nf * 16 + (l & 15)];
    bs[nf] = bias[n0 + nf * 16 + (l & 15)];
  }
  float xs[2][4];
  #pragma unroll
  for (int mf = 0; mf < 2; ++mf)
    #pragma unroll
    for (int j = 0; j < 4; ++j)
      xs[mf][j] = xscale[row0 + mf * 16 + (l >> 4) * 4 + j];

  v4f facc[2][4];
  #pragma unroll
  for (int mf = 0; mf < 2; ++mf)
    #pragma unroll
    for (int nf = 0; nf < 4; ++nf)
      #pragma unroll
      for (int j = 0; j < 4; ++j)
        facc[mf][nf][j] = (float)acc[mf][nf][j] * xs[mf][j] * sc[nf];

  // outlier fp phase: K=256 in 8 steps of 32
  #pragma unroll
  for (int ks = 0; ks < 8; ++ks) {
    const int kk = ks * 32 + (l >> 4) * 8;
    half8 ah[2];
    #pragma unroll
    for (int mf = 0; mf < 2; ++mf) {
      const int row = row0 + mf * 16 + (l & 15);
      ah[mf] = *(const half8*)(act + row * FP_F + kk);
    }
    half8 bh[4];
    #pragma unroll
    for (int nf = 0; nf < 4; ++nf) {
      const float* wr = wc + (size_t)(n0 + nf * 16 + (l & 15)) * FP_F + kk;
      v4f w0 = *(const v4f*)(wr);
      v4f w1 = *(const v4f*)(wr + 4);
      half8 hb;
      #pragma unroll
      for (int j = 0; j < 4; ++j) {
        hb[j] = (_Float16)w0[j];
        hb[4 + j] = (_Float16)w1[j];
      }
      bh[nf] = hb;
    }
    #pragma unroll
    for (int mf = 0; mf < 2; ++mf)
      #pragma unroll
      for (int nf = 0; nf < 4; ++nf)
        facc[mf][nf] = __builtin_amdgcn_mfma_f32_16x16x32_f16(
            ah[mf], bh[nf], facc[mf][nf], 0, 0, 0);
  }

  #pragma unroll
  for (int mf = 0; mf < 2; ++mf)
    #pragma unroll
    for (int nf = 0; nf < 4; ++nf) {
      const int col = n0 + nf * 16 + (l & 15);
      #pragma unroll
      for (int j = 0; j < 4; ++j) {
        const int row = row0 + mf * 16 + (l >> 4) * 4 + j;
        out[(size_t)row * OUT_F + col] = facc[mf][nf][j] + bs[nf];
      }
    }
}

// ---------------- fallback (round-3 path) if ws is too small ----------------
__global__ __launch_bounds__(256) void gemm_fallback(
    const signed char* __restrict__ qx, const int* __restrict__ qw,
    const float* __restrict__ scol, const float* __restrict__ wc,
    const float* __restrict__ bias, const _Float16* __restrict__ act,
    const float* __restrict__ xscale, float* __restrict__ out)
{
  __shared__ __align__(16) signed char blds[2][2048];
  const int tid = threadIdx.x;
  const int w = tid >> 6;
  const int l = tid & 63;
  const int mtile = blockIdx.x & 1;
  const int ntile = blockIdx.x >> 1;
  const int n0 = ntile * 32;
  const int row0 = mtile * 256 + w * 64;

  const int r = tid >> 3;
  const int* bsrc = qw + (size_t)(n0 + r) * IN_F + (tid & 7) * 4;
  signed char* bw0 = &blds[0][0] + (r >> 4) * 1024 +
                     ((r & 15) + 16 * ((tid & 7) >> 2)) * 16 + (tid & 3) * 4;

  const v4i* qx4 = (const v4i*)qx;
  const int aBase = (row0 >> 4) * 4096 + l;

  v4i gr[4][2];
  v4i ar[2][4];

  #pragma unroll
  for (int s = 0; s < 4; ++s) {
    gr[s][0] = *(const v4i*)(bsrc + s * 64);
    gr[s][1] = *(const v4i*)(bsrc + s * 64 + 32);
  }
  #pragma unroll
  for (int mf = 0; mf < 4; ++mf)
    ar[0][mf] = qx4[aBase + mf * 4096];

  *(int*)(bw0)       = pack4(gr[0][0]);
  *(int*)(bw0 + 512) = pack4(gr[0][1]);
  asm volatile("s_waitcnt lgkmcnt(0)" ::: "memory");
  __builtin_amdgcn_s_barrier();

  v4i acc[4][2] = {};

  for (int kb = 0; kb < 64; ++kb) {
    const int kf = (kb + 4 < 64) ? kb + 4 : 63;
    gr[kb & 3][0] = *(const v4i*)(bsrc + kf * 64);
    gr[kb & 3][1] = *(const v4i*)(bsrc + kf * 64 + 32);
    const int ka = (kb + 1 < 64) ? kb + 1 : 63;
    #pragma unroll
    for (int mf = 0; mf < 4; ++mf)
      ar[(kb + 1) & 1][mf] = qx4[aBase + mf * 4096 + ka * 64];
    {
      signed char* d = bw0 + ((kb + 1) & 1) * 2048;
      *(int*)(d)       = pack4(gr[(kb + 1) & 3][0]);
      *(int*)(d + 512) = pack4(gr[(kb + 1) & 3][1]);
    }
    const signed char* rb = &blds[kb & 1][0];
    v4i b[2];
    #pragma unroll
    for (int nf = 0; nf < 2; ++nf)
      b[nf] = *(const v4i*)(rb + nf * 1024 + l * 16);
    #pragma unroll
    for (int mf = 0; mf < 4; ++mf)
      #pragma unroll
      for (int nf = 0; nf < 2; ++nf)
        acc[mf][nf] = __builtin_amdgcn_mfma_i32_16x16x64_i8(
            ar[kb & 1][mf], b[nf], acc[mf][nf], 0, 0, 0);
    asm volatile("s_waitcnt lgkmcnt(0)" ::: "memory");
    __builtin_amdgcn_s_barrier();
  }

  float sc[2], bs[2];
  #pragma unroll
  for (int nf = 0; nf < 2; ++nf) {
    sc[nf] = scol[n0 + nf * 16 + (l & 15)];
    bs[nf] = bias[n0 + nf * 16 + (l & 15)];
  }
  float xs[4][4];
  #pragma unroll
  for (int mf = 0; mf < 4; ++mf)
    #pragma unroll
    for (int j = 0; j < 4; ++j)
      xs[mf][j] = xscale[row0 + mf * 16 + (l >> 4) * 4 + j];

  v4f facc[4][2];
  #pragma unroll
  for (int mf = 0; mf < 4; ++mf)
    #pragma unroll
    for (int nf = 0; nf < 2; ++nf)
      #pragma unroll
      for (int j = 0; j < 4; ++j)
        facc[mf][nf][j] = (float)acc[mf][nf][j] * xs[mf][j] * sc[nf];

  #pragma unroll
  for (int ks = 0; ks < 8; ++ks) {
    const int kk = ks * 32 + (l >> 4) * 8;
    half8 ah[4];
    #pragma unroll
    for (int mf = 0; mf < 4; ++mf) {
      const int row = row0 + mf * 16 + (l & 15);
      ah[mf] = *(const half8*)(act + row * FP_F + kk);
    }
    half8 bh[2];
    #pragma unroll
    for (int nf = 0; nf < 2; ++nf) {
      const float* wr = wc + (size_t)(n0 + nf * 16 + (l & 15)) * FP_F + kk;
      v4f w0 = *(const v4f*)(wr);
      v4f w1 = *(const v4f*)(wr + 4);
      half8 hb;
      #pragma unroll
      for (int j = 0; j < 4; ++j) {
        hb[j] = (_Float16)w0[j];
        hb[4 + j] = (_Float16)w1[j];
      }
      bh[nf] = hb;
    }
    #pragma unroll
    for (int mf = 0; mf < 4; ++mf)
      #pragma unroll
      for (int nf = 0; nf < 2; ++nf)
        facc[mf][nf] = __builtin_amdgcn_mfma_f32_16x16x32_f16(
            ah[mf], bh[nf], facc[mf][nf], 0, 0, 0);
  }

  #pragma unroll
  for (int mf = 0; mf < 4; ++mf)
    #pragma unroll
    for (int nf = 0; nf < 2; ++nf) {
      const int col = n0 + nf * 16 + (l & 15);
      #pragma unroll
      for (int j = 0; j < 4; ++j) {
        const int row = row0 + mf * 16 + (l >> 4) * 4 + j;
        out[(size_t)row * OUT_F + col] = facc[mf][nf][j] + bs[nf];
      }
    }
}

extern "C" void kernel_launch(void* const* d_in, const int* in_sizes, int n_in,
                              void* d_out, int out_size, void* d_ws, size_t ws_size,
                              hipStream_t stream) {
  const float* x      = (const float*)d_in[0];
  const int*   qw     = (const int*)d_in[1];
  const float* scol   = (const float*)d_in[2];
  const float* wcache = (const float*)d_in[3];
  const int*   ind    = (const int*)d_in[4];
  const float* bias   = (const float*)d_in[5];
  float* out = (float*)d_out;

  const size_t qx_off  = 0;
  const size_t act_off = (size_t)NROWS * IN_F;                      // 2 MB
  const size_t xs_off  = act_off + (size_t)NROWS * FP_F * 2;        // +256 KB
  const size_t qb_off  = xs_off + (size_t)NROWS * 4;                // +2 KB
  const size_t need    = qb_off + (size_t)OUT_F * IN_F;             // +45 MB

  signed char* qx = (signed char*)d_ws + qx_off;
  _Float16* act   = (_Float16*)((char*)d_ws + act_off);
  float* xscale   = (float*)((char*)d_ws + xs_off);
  signed char* qb = (signed char*)d_ws + qb_off;

  if (ws_size >= need) {
    prep_kernel<<<NROWS + NPACK, 256, 0, stream>>>(x, ind, qw, qx, act, xscale, qb);
    gemm_kernel<<<NGEMM, 256, 0, stream>>>(
        qx, qb, scol, wcache, bias, act, xscale, out);
  } else {
    prep_kernel<<<NROWS, 256, 0, stream>>>(x, ind, qw, qx, act, xscale, qb);
    gemm_fallback<<<(OUT_F / 32) * 2, 256, 0, stream>>>(
        qx, qw, scol, wcache, bias, act, xscale, out);
  }
}